// Round 5
// baseline (1948.247 us; speedup 1.0000x reference)
//
#include <hip/hip_runtime.h>

// ---------------------------------------------------------------------------
// MyModel: BiLSTM1(token) + maxpool -> softmax7/avg_lab -> MLP -> top-k gate
//          -> BiLSTM2(sentence seq, batch=1) -> log_softmax CE + penalty
// N=1024, L=128, D=300, H=150, G=4H=600
// ---------------------------------------------------------------------------

typedef _Float16 f16;
typedef _Float16 half8 __attribute__((ext_vector_type(8)));
typedef float    floatx4 __attribute__((ext_vector_type(4)));

#define MFMA16(a, b, c) __builtin_amdgcn_mfma_f32_16x16x32_f16((a), (b), (c), 0, 0, 0)
#define LOG2E 1.44269504f

__device__ __forceinline__ float rcp_(float x) { return __builtin_amdgcn_rcpf(x); }
__device__ __forceinline__ float ex2_(float x) { return __builtin_amdgcn_exp2f(x); }
__device__ __forceinline__ float sigm_(float x) { return rcp_(1.0f + ex2_(-LOG2E * x)); }
__device__ __forceinline__ float tanh_(float x) { return 1.0f - 2.0f * rcp_(1.0f + ex2_(2.0f * LOG2E * x)); }

// LDS-only barrier: waits LDS ops, leaves global loads/stores in flight.
__device__ __forceinline__ void bar_lds() {
    asm volatile("s_waitcnt lgkmcnt(0)" ::: "memory");
    __builtin_amdgcn_s_barrier();
}

// ---------------------------------------------------------------------------
// K0a: pack fp32 weights into zero-padded f16 buffers.
// mode 0: plain pad.
// mode 1: LSTM input weights, gate-interleaved rows (packed row r=w*64+g*16+rr
//         -> src gate g, j=w*16+rr) + bias folded at col 300 (A supplies 1.0).
// mode 2: LSTM recurrent weights, same row interleave, no bias.
// ---------------------------------------------------------------------------
struct PackA { const float* s[9]; f16* d[9]; const float* bias[9]; };

__global__ void pack_k(PackA pa) {
    const int R[9]    = {640, 640, 320, 640, 640, 640, 640, 640, 640};
    const int C[9]    = {320, 320, 640, 320, 320, 160, 160, 160, 160};
    const int rows[9] = {600, 600, 300, 600, 600, 600, 600, 600, 600};
    const int cols[9] = {300, 300, 600, 300, 300, 150, 150, 150, 150};
    const int mode[9] = {1, 1, 0, 1, 1, 2, 2, 2, 2};
    int j = blockIdx.y;
    int idx = blockIdx.x * 256 + threadIdx.x;
    int RC = R[j] * C[j];
    if (idx >= RC) return;
    int r = idx / C[j], c = idx % C[j];
    float v = 0.0f;
    if (mode[j] == 0) {
        if (r < rows[j] && c < cols[j]) v = pa.s[j][r * cols[j] + c];
    } else {
        int w = r >> 6, g = (r >> 4) & 3, rr = r & 15;
        int jj = w * 16 + rr;
        if (jj < 150) {
            int srow = g * 150 + jj;
            if (mode[j] == 1) {
                if (c < 300) v = pa.s[j][srow * 300 + c];
                else if (c == 300) v = pa.bias[j][srow];
            } else {
                if (c < 150) v = pa.s[j][srow * 150 + c];
            }
        }
    }
    pa.d[j][idx] = (f16)v;
}

// K0b: exclusive prefix sum of lengths -> compact row offsets
__global__ __launch_bounds__(1024) void scan_k(const int* __restrict__ len, int* __restrict__ coff) {
    __shared__ int a[1024];
    int t = threadIdx.x;
    a[t] = len[t];
    __syncthreads();
    for (int off = 1; off < 1024; off <<= 1) {
        int v = (t >= off) ? a[t - off] : 0;
        __syncthreads();
        a[t] += v;
        __syncthreads();
    }
    coff[t] = a[t] - len[t];
}

// ---------------------------------------------------------------------------
// Dual-B NT GEMM (f16 out). onecol: global k index where A is treated as 1.0
// beyond Keff (bias-fold column). blockIdx.y: (y>>1)=B-select, (y&1)=col half.
// ---------------------------------------------------------------------------
template <bool COMPACT>
__global__ __launch_bounds__(256, 2) void gemm2_nt(
    const float* __restrict__ A, int lda, int Keff, int Ksteps, int onecol,
    const f16* __restrict__ B0, f16* __restrict__ C0,
    const f16* __restrict__ B1, f16* __restrict__ C1,
    int ldc, const int* __restrict__ len, const int* __restrict__ coff) {
    __shared__ f16 As[128][40];
    __shared__ f16 Bs[320][40];

    const int tid = threadIdx.x;
    const int m0 = blockIdx.x * 128;
    const int sel = blockIdx.y >> 1;
    const int n0 = (blockIdx.y & 1) * 320;
    const f16* B = sel ? B1 : B0;
    f16* Ch = sel ? C1 : C0;
    const int ldb = Ksteps * 32;
    const int wv = tid >> 6, ln = tid & 63;
    const int lq = ln >> 4, lr = ln & 15;

    int ln_ = 0x7fffffff, co = 0;
    if (COMPACT) { int sn = blockIdx.x; ln_ = len[sn]; co = coff[sn]; }
    const bool act = !COMPACT || (wv * 32 < ln_);

    floatx4 acc[2][20];
#pragma unroll
    for (int s = 0; s < 2; ++s)
#pragma unroll
        for (int nt = 0; nt < 20; ++nt) acc[s][nt] = 0;

    for (int kt = 0; kt < Ksteps; ++kt) {
        {
            int r = tid >> 1, c0 = (tid & 1) * 16;
            if (!COMPACT || r < ln_) {
                int gk = kt * 32 + c0;
                const float* ap = A + (size_t)(m0 + r) * lda + gk;
                float v[16];
                if (gk + 16 <= Keff) {
                    const float4* p4 = (const float4*)ap;
                    float4 a0 = p4[0], a1 = p4[1], a2 = p4[2], a3 = p4[3];
                    v[0]=a0.x; v[1]=a0.y; v[2]=a0.z; v[3]=a0.w;
                    v[4]=a1.x; v[5]=a1.y; v[6]=a1.z; v[7]=a1.w;
                    v[8]=a2.x; v[9]=a2.y; v[10]=a2.z; v[11]=a2.w;
                    v[12]=a3.x; v[13]=a3.y; v[14]=a3.z; v[15]=a3.w;
                } else {
#pragma unroll
                    for (int j = 0; j < 16; ++j)
                        v[j] = (gk + j < Keff) ? ap[j] : ((gk + j == onecol) ? 1.0f : 0.0f);
                }
                half8 h0, h1;
#pragma unroll
                for (int j = 0; j < 8; ++j) { h0[j] = (f16)v[j]; h1[j] = (f16)v[8 + j]; }
                *(half8*)&As[r][c0] = h0;
                *(half8*)&As[r][c0 + 8] = h1;
            }
        }
        {
            int q = tid & 3;
#pragma unroll
            for (int i = 0; i < 5; ++i) {
                int rb = (tid >> 2) + i * 64;
                half8 bv = *(const half8*)(B + (size_t)(n0 + rb) * ldb + kt * 32 + q * 8);
                *(half8*)&Bs[rb][q * 8] = bv;
            }
        }
        bar_lds();
        if (act) {
            half8 af0 = *(const half8*)&As[wv * 32 + lr][lq * 8];
            half8 af1 = *(const half8*)&As[wv * 32 + 16 + lr][lq * 8];
#pragma unroll
            for (int nt = 0; nt < 20; ++nt) {
                half8 bf = *(const half8*)&Bs[nt * 16 + lr][lq * 8];
                acc[0][nt] = MFMA16(af0, bf, acc[0][nt]);
                acc[1][nt] = MFMA16(af1, bf, acc[1][nt]);
            }
        }
        bar_lds();
    }
    if (!act) return;
#pragma unroll
    for (int s = 0; s < 2; ++s)
#pragma unroll
        for (int nt = 0; nt < 20; ++nt)
#pragma unroll
            for (int rr = 0; rr < 4; ++rr) {
                int t = wv * 32 + s * 16 + lq * 4 + rr;
                int col = n0 + nt * 16 + lr;
                float v = acc[s][nt][rr];
                if (COMPACT) {
                    if (t < ln_) Ch[(size_t)(co + t) * ldc + col] = (f16)v;
                } else {
                    Ch[(size_t)(m0 + t) * ldc + col] = (f16)v;
                }
            }
}

// ---------------------------------------------------------------------------
// Single-output NT GEMM fp32 out + bias + relu (MLP stage only)
// ---------------------------------------------------------------------------
__global__ __launch_bounds__(256, 2) void gemm_mlp(
    const float* __restrict__ A, int lda, int Ksteps,
    const f16* __restrict__ B, const float* __restrict__ bias,
    float* __restrict__ Cf, int ldc) {
    __shared__ f16 As[128][40];
    __shared__ f16 Bs[320][40];
    const int tid = threadIdx.x;
    const int m0 = blockIdx.x * 128;
    const int ldb = Ksteps * 32;
    const int wv = tid >> 6, ln = tid & 63;
    const int lq = ln >> 4, lr = ln & 15;

    floatx4 acc[2][20];
#pragma unroll
    for (int s = 0; s < 2; ++s)
#pragma unroll
        for (int nt = 0; nt < 20; ++nt) acc[s][nt] = 0;

    for (int kt = 0; kt < Ksteps; ++kt) {
        {
            int r = tid >> 1, c0 = (tid & 1) * 16;
            const float4* p4 = (const float4*)(A + (size_t)(m0 + r) * lda + kt * 32 + c0);
            float4 a0 = p4[0], a1 = p4[1], a2 = p4[2], a3 = p4[3];
            half8 h0, h1;
            h0[0]=(f16)a0.x; h0[1]=(f16)a0.y; h0[2]=(f16)a0.z; h0[3]=(f16)a0.w;
            h0[4]=(f16)a1.x; h0[5]=(f16)a1.y; h0[6]=(f16)a1.z; h0[7]=(f16)a1.w;
            h1[0]=(f16)a2.x; h1[1]=(f16)a2.y; h1[2]=(f16)a2.z; h1[3]=(f16)a2.w;
            h1[4]=(f16)a3.x; h1[5]=(f16)a3.y; h1[6]=(f16)a3.z; h1[7]=(f16)a3.w;
            *(half8*)&As[r][c0] = h0;
            *(half8*)&As[r][c0 + 8] = h1;
        }
        {
            int q = tid & 3;
#pragma unroll
            for (int i = 0; i < 5; ++i) {
                int rb = (tid >> 2) + i * 64;
                half8 bv = *(const half8*)(B + (size_t)rb * ldb + kt * 32 + q * 8);
                *(half8*)&Bs[rb][q * 8] = bv;
            }
        }
        bar_lds();
        half8 af0 = *(const half8*)&As[wv * 32 + lr][lq * 8];
        half8 af1 = *(const half8*)&As[wv * 32 + 16 + lr][lq * 8];
#pragma unroll
        for (int nt = 0; nt < 20; ++nt) {
            half8 bf = *(const half8*)&Bs[nt * 16 + lr][lq * 8];
            acc[0][nt] = MFMA16(af0, bf, acc[0][nt]);
            acc[1][nt] = MFMA16(af1, bf, acc[1][nt]);
        }
        bar_lds();
    }
#pragma unroll
    for (int s = 0; s < 2; ++s)
#pragma unroll
        for (int nt = 0; nt < 20; ++nt)
#pragma unroll
            for (int rr = 0; rr < 4; ++rr) {
                int t = wv * 32 + s * 16 + lq * 4 + rr;
                int col = nt * 16 + lr;
                float v = acc[s][nt][rr];
                if (col < 300) v += bias[col];
                v = fmaxf(v, 0.0f);
                Cf[(size_t)(m0 + t) * ldc + col] = v;
            }
}

// ---------------------------------------------------------------------------
// K2: LSTM1 recurrence, 16 sentences/WG, 640 thr (10 waves = 10 j-tiles).
// Gate-interleaved weights: lane (wv,lq,lr,reg rr) owns all 4 gates of
// (sentence m=lq*4+rr, element j=wv*16+lr) -> elementwise + c + pool fully in
// registers. LDS = double-buffered h only; ONE barrier/step. Xg prefetched
// depth-2 via pointer+imm offsets.
// ---------------------------------------------------------------------------
__global__ __launch_bounds__(640, 1) void lstm1_k(
    const f16* __restrict__ XgF, const f16* __restrict__ XgB,
    const f16* __restrict__ WhF, const f16* __restrict__ WhB,
    float* __restrict__ sent,
    const int* __restrict__ len, const int* __restrict__ coff, int dirbase) {
    const int dir = dirbase + blockIdx.y;
    const f16* Xg = dir ? XgB : XgF;
    const f16* Whh = dir ? WhB : WhF;
    __shared__ f16 hbuf[2][16][168];   // stride 336 B: af b128 reads 2-way (free)
    __shared__ int lens_s[16], coff_s[16];

    const int tid = threadIdx.x;
    const int wv = tid >> 6, ln = tid & 63;
    const int lq = ln >> 4, lr = ln & 15;
    const int sb = blockIdx.x * 16;

    if (tid < 16) { lens_s[tid] = len[sb + tid]; coff_s[tid] = coff[sb + tid]; }
    for (int i = tid; i < 2 * 16 * 168; i += 640) (&hbuf[0][0][0])[i] = (f16)0.0f;
    __syncthreads();

    int len_m[4], cof_m[4];
#pragma unroll
    for (int rr = 0; rr < 4; ++rr) { len_m[rr] = lens_s[lq * 4 + rr]; cof_m[rr] = coff_s[lq * 4 + rr]; }
    int maxlen = 0;
#pragma unroll
    for (int j = 0; j < 16; ++j) maxlen = max(maxlen, lens_s[j]);
    const int mlen2 = (maxlen + 1) & ~1;   // extra step harmless (pool guarded)

    const int cb = wv * 64;
    half8 bf[4][5];
#pragma unroll
    for (int g = 0; g < 4; ++g)
#pragma unroll
        for (int kt = 0; kt < 5; ++kt)
            bf[g][kt] = *(const half8*)(Whh + (size_t)(cb + g * 16 + lr) * 160 + kt * 32 + lq * 8);

    float c_r[4] = {0, 0, 0, 0};
    float pool_r[4] = {-1e30f, -1e30f, -1e30f, -1e30f};

    auto teF = [&](int rr, int t) { return dir ? max(len_m[rr] - 1 - t, 0) : min(t, len_m[rr] - 1); };

    f16 xa[4][4], xb[4][4];   // [g][rr], ping-pong depth 2
#pragma unroll
    for (int rr = 0; rr < 4; ++rr) {
        const f16* p0 = Xg + (size_t)(cof_m[rr] + teF(rr, 0)) * 640 + cb + lr;
        const f16* p1 = Xg + (size_t)(cof_m[rr] + teF(rr, 1)) * 640 + cb + lr;
#pragma unroll
        for (int g = 0; g < 4; ++g) { xa[g][rr] = p0[g * 16]; xb[g][rr] = p1[g * 16]; }
    }
    const floatx4 z4 = {0, 0, 0, 0};

    auto step = [&](int t, f16 (&X)[4][4]) {
        const int cur = t & 1, nxt = cur ^ 1;
        half8 af[5];
#pragma unroll
        for (int kt = 0; kt < 5; ++kt) af[kt] = *(const half8*)&hbuf[cur][lr][kt * 32 + lq * 8];
        float xg[4][4];
#pragma unroll
        for (int g = 0; g < 4; ++g)
#pragma unroll
            for (int rr = 0; rr < 4; ++rr) xg[g][rr] = (float)X[g][rr];
        // refill X for step t+2 (te clamps keep it in-bounds)
#pragma unroll
        for (int rr = 0; rr < 4; ++rr) {
            const f16* p = Xg + (size_t)(cof_m[rr] + teF(rr, t + 2)) * 640 + cb + lr;
#pragma unroll
            for (int g = 0; g < 4; ++g) X[g][rr] = p[g * 16];
        }
        float gate[4][4];
#pragma unroll
        for (int g = 0; g < 4; ++g) {
            floatx4 a0 = MFMA16(af[0], bf[g][0], z4);
            floatx4 a1 = MFMA16(af[1], bf[g][1], z4);
            a0 = MFMA16(af[2], bf[g][2], a0);
            a1 = MFMA16(af[3], bf[g][3], a1);
            a0 = MFMA16(af[4], bf[g][4], a0);
#pragma unroll
            for (int rr = 0; rr < 4; ++rr) gate[g][rr] = a0[rr] + a1[rr] + xg[g][rr];
        }
#pragma unroll
        for (int rr = 0; rr < 4; ++rr) {
            float cn = sigm_(gate[1][rr]) * c_r[rr] + sigm_(gate[0][rr]) * tanh_(gate[2][rr]);
            float hn = sigm_(gate[3][rr]) * tanh_(cn);
            c_r[rr] = cn;
            if (t < len_m[rr]) pool_r[rr] = fmaxf(pool_r[rr], hn);
            hbuf[nxt][lq * 4 + rr][wv * 16 + lr] = (f16)hn;
        }
        bar_lds();
    };

    for (int t2 = 0; t2 < mlen2; t2 += 2) {
        step(t2, xa);
        step(t2 + 1, xb);
    }

    const int j = wv * 16 + lr;
    if (j < 150) {
#pragma unroll
        for (int rr = 0; rr < 4; ++rr)
            sent[(size_t)(sb + lq * 4 + rr) * 300 + dir * 150 + j] = pool_r[rr];
    }
}

// ---------------------------------------------------------------------------
// K4a: per sentence: ex softmax(7), ex_pre argmax, avg_lab, build A2 fp32
// ---------------------------------------------------------------------------
__global__ void k4a(const float* __restrict__ sent, const float* __restrict__ w_ex,
                    const float* __restrict__ b_ex, const float* __restrict__ lab,
                    float* __restrict__ A2, int* __restrict__ expre) {
    int n = blockIdx.x, l = threadIdx.x;
    float s[5];
#pragma unroll
    for (int i = 0; i < 5; ++i) { int d = l + 64 * i; s[i] = (d < 300) ? sent[(size_t)n * 300 + d] : 0.0f; }
    float logit[7];
#pragma unroll
    for (int c = 0; c < 7; ++c) {
        float p = 0.0f;
#pragma unroll
        for (int i = 0; i < 5; ++i) { int d = l + 64 * i; if (d < 300) p += s[i] * w_ex[c * 300 + d]; }
#pragma unroll
        for (int off = 32; off > 0; off >>= 1) p += __shfl_xor(p, off);
        logit[c] = p + b_ex[c];
    }
    float mx = logit[0];
#pragma unroll
    for (int c = 1; c < 7; ++c) mx = fmaxf(mx, logit[c]);
    float e[7], ssum = 0.0f;
#pragma unroll
    for (int c = 0; c < 7; ++c) { e[c] = ex2_(LOG2E * (logit[c] - mx)); ssum += e[c]; }
    int best = 0;
#pragma unroll
    for (int c = 1; c < 7; ++c) if (logit[c] > logit[best]) best = c;
    if (l == 0) expre[n] = best;
    float inv = rcp_(ssum);
#pragma unroll
    for (int i = 0; i < 5; ++i) {
        int d = l + 64 * i;
        if (d < 300) {
            float al = 0.0f;
#pragma unroll
            for (int c = 0; c < 7; ++c) al += e[c] * inv * lab[c * 300 + d];
            A2[(size_t)n * 640 + d] = s[i];
            A2[(size_t)n * 640 + 300 + d] = al;
        }
    }
    if (l < 40) A2[(size_t)n * 640 + 600 + l] = 0.0f;
}

// ---------------------------------------------------------------------------
// K5: score softmax over N, exact top-512, penalty partial, mixed build.
// ---------------------------------------------------------------------------
__global__ __launch_bounds__(1024) void k5(const float* __restrict__ joint,
                                           const float* __restrict__ sent,
                                           const float* __restrict__ w_sc,
                                           const float* __restrict__ b_sc,
                                           const int* __restrict__ gold,
                                           const int* __restrict__ expre,
                                           float* __restrict__ mixed,
                                           float* __restrict__ pen_out,
                                           float* __restrict__ dout) {
    __shared__ float arr[1024];
    __shared__ float red[1024];
    int n = threadIdx.x;
    const float4* jr = (const float4*)(joint + (size_t)n * 320);
    const float4* wr = (const float4*)w_sc;
    float sc = b_sc[0];
    for (int q = 0; q < 75; ++q) {
        float4 a = jr[q], w = wr[q];
        sc += a.x * w.x + a.y * w.y + a.z * w.z + a.w * w.w;
    }
    float sg = sigm_(sc);
    arr[n] = sg;
    red[n] = sg;
    __syncthreads();
    for (int s = 512; s > 0; s >>= 1) { if (n < s) red[n] = fmaxf(red[n], red[n + s]); __syncthreads(); }
    float mx = red[0];
    __syncthreads();
    float ex = ex2_(LOG2E * (sg - mx));
    red[n] = ex;
    __syncthreads();
    for (int s = 512; s > 0; s >>= 1) { if (n < s) red[n] += red[n + s]; __syncthreads(); }
    float score = ex * rcp_(red[0]);
    __syncthreads();
    int cnt = 0;
    for (int j = 0; j < 1024; ++j) {
        float vj = arr[j];
        cnt += (vj > sg) || (vj == sg && j < n);
    }
    bool top = cnt < 512;
    bool wrong = gold[n] != expre[n];
    float contrib = wrong ? (top ? 1.5f * score : 0.0f) : (top ? 0.0f : -1.5f * score);
    red[n] = contrib;
    __syncthreads();
    for (int s = 512; s > 0; s >>= 1) { if (n < s) red[n] += red[n + s]; __syncthreads(); }
    if (n == 0) { pen_out[0] = red[0]; dout[1024] = 0.0f; }
    const float4* sr = (const float4*)(sent + (size_t)n * 300);
    float4* mr = (float4*)(mixed + (size_t)n * 320);
    for (int q = 0; q < 75; ++q) mr[q] = top ? jr[q] : sr[q];
    float4 one = {1.0f, 0.0f, 0.0f, 0.0f};
    mr[75] = one;
    float4 z = {0, 0, 0, 0};
    for (int q = 76; q < 80; ++q) mr[q] = z;
}

// ---------------------------------------------------------------------------
// K7: LSTM2, 1024 steps, 2 WGs. In-reg gates; zero-C MFMA init (no acc movs);
// running-pointer depth-2 G2 prefetch (2-row overrun stays inside ws: G2F and
// G2B are adjacent); one LDS barrier/step; 2x-unrolled.
// ---------------------------------------------------------------------------
__global__ __launch_bounds__(640, 1) void lstm2_k(
    const f16* __restrict__ G2f, const f16* __restrict__ G2b,
    const f16* __restrict__ H2f, const f16* __restrict__ H2b,
    float* __restrict__ out2) {
    const int dir = blockIdx.x;
    const f16* G2 = dir ? G2b : G2f;
    const f16* Whh = dir ? H2b : H2f;
    __shared__ f16 hl[2][160];

    const int tid = threadIdx.x;
    const int wv = tid >> 6, ln = tid & 63;
    const int lq = ln >> 4, lr = ln & 15;
    const int jme = wv * 16 + lr;
    for (int i = tid; i < 320; i += 640) ((f16*)hl)[i] = (f16)0.0f;
    __syncthreads();

    float c = 0.0f;

    half8 bf[4][5];
#pragma unroll
    for (int g = 0; g < 4; ++g)
#pragma unroll
        for (int kt = 0; kt < 5; ++kt)
            bf[g][kt] = *(const half8*)(Whh + (size_t)(wv * 64 + g * 16 + lr) * 160 + kt * 32 + lq * 8);

    const ptrdiff_t dstep = dir ? -640 : 640;
    const f16* gp = G2 + (size_t)(dir ? 1023 : 0) * 640 + wv * 64 + lr;
    f16 xa[4], xb[4];
#pragma unroll
    for (int g = 0; g < 4; ++g) xa[g] = gp[g * 16];
    gp += dstep;
#pragma unroll
    for (int g = 0; g < 4; ++g) xb[g] = gp[g * 16];
    gp += dstep;
    const floatx4 z4 = {0, 0, 0, 0};

    auto step = [&](int s, f16 (&X)[4]) {
        const int p = s & 1;
        const int row = dir ? 1023 - s : s;
        half8 af[5];
#pragma unroll
        for (int kt = 0; kt < 5; ++kt) af[kt] = *(const half8*)&hl[p][kt * 32 + lq * 8];
        float xg[4];
#pragma unroll
        for (int g = 0; g < 4; ++g) xg[g] = (float)X[g];
#pragma unroll
        for (int g = 0; g < 4; ++g) X[g] = gp[g * 16];   // refill for s+2
        gp += dstep;
        float gate[4];
#pragma unroll
        for (int g = 0; g < 4; ++g) {
            floatx4 a0 = MFMA16(af[0], bf[g][0], z4);
            floatx4 a1 = MFMA16(af[1], bf[g][1], z4);
            a0 = MFMA16(af[2], bf[g][2], a0);
            a1 = MFMA16(af[3], bf[g][3], a1);
            a0 = MFMA16(af[4], bf[g][4], a0);
            gate[g] = a0[0] + a1[0] + xg[g];
        }
        float cn = sigm_(gate[1]) * c + sigm_(gate[0]) * tanh_(gate[2]);
        float hn = sigm_(gate[3]) * tanh_(cn);
        c = cn;
        if (lq == 0 && jme < 150) {
            hl[p ^ 1][jme] = (f16)hn;
            out2[(size_t)row * 300 + dir * 150 + jme] = hn;
        }
        bar_lds();
    };

    for (int s2 = 0; s2 < 1024; s2 += 2) {
        step(s2, xa);
        step(s2 + 1, xb);
    }
}

// ---------------------------------------------------------------------------
// K8: tag logits, log_softmax, argmax -> d_out[0..1023]; CE partial + pen
// ---------------------------------------------------------------------------
__global__ __launch_bounds__(256) void k8(const float* __restrict__ out2,
                                          const float* __restrict__ w_tag,
                                          const float* __restrict__ b_tag,
                                          const int* __restrict__ gold,
                                          const float* __restrict__ pen,
                                          float* __restrict__ dout) {
    __shared__ float wt[7][304];
    __shared__ float red[128];
    const int tid = threadIdx.x;
    for (int i = tid; i < 2100; i += 256) wt[i / 300][i % 300] = w_tag[i];
    __syncthreads();
    float ce = 0.0f;
    if (tid < 128) {
        int n = blockIdx.x * 128 + tid;
        float lg[7];
#pragma unroll
        for (int c = 0; c < 7; ++c) lg[c] = b_tag[c];
        const float4* orow = (const float4*)(out2 + (size_t)n * 300);
        for (int q = 0; q < 75; ++q) {
            float4 v = orow[q];
#pragma unroll
            for (int c = 0; c < 7; ++c)
                lg[c] += v.x * wt[c][q * 4] + v.y * wt[c][q * 4 + 1] +
                         v.z * wt[c][q * 4 + 2] + v.w * wt[c][q * 4 + 3];
        }
        float mx = lg[0];
#pragma unroll
        for (int c = 1; c < 7; ++c) mx = fmaxf(mx, lg[c]);
        float se = 0.0f;
#pragma unroll
        for (int c = 0; c < 7; ++c) se += ex2_(LOG2E * (lg[c] - mx));
        float lse = logf(se);
        int best = 0;
#pragma unroll
        for (int c = 1; c < 7; ++c) if (lg[c] > lg[best]) best = c;
        dout[n] = (float)best;
        ce = -(lg[gold[n]] - mx - lse);
    }
    if (tid < 128) red[tid] = ce;
    __syncthreads();
    for (int s = 64; s > 0; s >>= 1) { if (tid < s) red[tid] += red[tid + s]; __syncthreads(); }
    if (tid == 0) atomicAdd(&dout[1024], red[0] + (blockIdx.x == 0 ? pen[0] : 0.0f));
}

// ---------------------------------------------------------------------------
extern "C" void kernel_launch(void* const* d_in, const int* in_sizes, int n_in,
                              void* d_out, int out_size, void* d_ws, size_t ws_size,
                              hipStream_t stream) {
    const float* x       = (const float*)d_in[0];
    const int*   lengths = (const int*)d_in[1];
    const int*   gold    = (const int*)d_in[2];
    const float* w1f_ih  = (const float*)d_in[3];
    const float* w1f_hh  = (const float*)d_in[4];
    const float* b1f     = (const float*)d_in[5];
    const float* w1b_ih  = (const float*)d_in[6];
    const float* w1b_hh  = (const float*)d_in[7];
    const float* b1b     = (const float*)d_in[8];
    const float* lab     = (const float*)d_in[9];
    const float* w_ex    = (const float*)d_in[10];
    const float* b_ex    = (const float*)d_in[11];
    const float* w_mlp   = (const float*)d_in[12];
    const float* b_mlp   = (const float*)d_in[13];
    const float* w_sc    = (const float*)d_in[14];
    const float* b_sc    = (const float*)d_in[15];
    const float* w2f_ih  = (const float*)d_in[16];
    const float* w2f_hh  = (const float*)d_in[17];
    const float* b2f     = (const float*)d_in[18];
    const float* w2b_ih  = (const float*)d_in[19];
    const float* w2b_hh  = (const float*)d_in[20];
    const float* b2b     = (const float*)d_in[21];
    const float* w_tag   = (const float*)d_in[22];
    const float* b_tag   = (const float*)d_in[23];
    float* dout = (float*)d_out;
    char* ws = (char*)d_ws;

    size_t o = 0;
    auto alloc = [&](size_t bytes) { size_t r = o; o += (bytes + 255) & ~(size_t)255; return r; };
    size_t W1F  = alloc(640 * 320 * 2);
    size_t W1B  = alloc(640 * 320 * 2);
    size_t WMLP = alloc(320 * 640 * 2);
    size_t W2F  = alloc(640 * 320 * 2);
    size_t W2B  = alloc(640 * 320 * 2);
    size_t H1F  = alloc(640 * 160 * 2);
    size_t H1B  = alloc(640 * 160 * 2);
    size_t H2F  = alloc(640 * 160 * 2);
    size_t H2B  = alloc(640 * 160 * 2);
    size_t COFF = alloc(1024 * 4);
    size_t SENT = alloc((size_t)1024 * 300 * 4);
    size_t A2   = alloc((size_t)1024 * 640 * 4);
    size_t EXP  = alloc(1024 * 4);
    size_t JNT  = alloc((size_t)1024 * 320 * 4);
    size_t MIX  = alloc((size_t)1024 * 320 * 4);
    size_t G2F  = alloc((size_t)1024 * 640 * 2);   // keep G2F/G2B adjacent:
    size_t G2B  = alloc((size_t)1024 * 640 * 2);   // prefetch overrun lands here
    size_t OUT2 = alloc((size_t)1024 * 300 * 4);
    size_t PEN  = alloc(256);
    const size_t XGSZ = (size_t)131072 * 640 * 2;
    size_t XGF = alloc(XGSZ);
    bool bigws = (o + XGSZ) <= ws_size;
    size_t XGB = bigws ? alloc(XGSZ) : XGF;
    (void)in_sizes; (void)n_in; (void)out_size;

    PackA pa;
    pa.s[0] = w1f_ih; pa.d[0] = (f16*)(ws + W1F);  pa.bias[0] = b1f;
    pa.s[1] = w1b_ih; pa.d[1] = (f16*)(ws + W1B);  pa.bias[1] = b1b;
    pa.s[2] = w_mlp;  pa.d[2] = (f16*)(ws + WMLP); pa.bias[2] = nullptr;
    pa.s[3] = w2f_ih; pa.d[3] = (f16*)(ws + W2F);  pa.bias[3] = b2f;
    pa.s[4] = w2b_ih; pa.d[4] = (f16*)(ws + W2B);  pa.bias[4] = b2b;
    pa.s[5] = w1f_hh; pa.d[5] = (f16*)(ws + H1F);  pa.bias[5] = nullptr;
    pa.s[6] = w1b_hh; pa.d[6] = (f16*)(ws + H1B);  pa.bias[6] = nullptr;
    pa.s[7] = w2f_hh; pa.d[7] = (f16*)(ws + H2F);  pa.bias[7] = nullptr;
    pa.s[8] = w2b_hh; pa.d[8] = (f16*)(ws + H2B);  pa.bias[8] = nullptr;
    pack_k<<<dim3(800, 9), 256, 0, stream>>>(pa);
    scan_k<<<1, 1024, 0, stream>>>(lengths, (int*)(ws + COFF));

    const int* coffp = (const int*)(ws + COFF);
    if (bigws) {
        gemm2_nt<true><<<dim3(1024, 4), 256, 0, stream>>>(
            x, 300, 300, 10, 300,
            (const f16*)(ws + W1F), (f16*)(ws + XGF),
            (const f16*)(ws + W1B), (f16*)(ws + XGB),
            640, lengths, coffp);
        lstm1_k<<<dim3(64, 2), 640, 0, stream>>>(
            (const f16*)(ws + XGF), (const f16*)(ws + XGB),
            (const f16*)(ws + H1F), (const f16*)(ws + H1B),
            (float*)(ws + SENT), lengths, coffp, 0);
    } else {
        gemm2_nt<true><<<dim3(1024, 2), 256, 0, stream>>>(
            x, 300, 300, 10, 300,
            (const f16*)(ws + W1F), (f16*)(ws + XGF),
            (const f16*)(ws + W1F), (f16*)(ws + XGF),
            640, lengths, coffp);
        lstm1_k<<<dim3(64, 1), 640, 0, stream>>>(
            (const f16*)(ws + XGF), (const f16*)(ws + XGF),
            (const f16*)(ws + H1F), (const f16*)(ws + H1F),
            (float*)(ws + SENT), lengths, coffp, 0);
        gemm2_nt<true><<<dim3(1024, 2), 256, 0, stream>>>(
            x, 300, 300, 10, 300,
            (const f16*)(ws + W1B), (f16*)(ws + XGF),
            (const f16*)(ws + W1B), (f16*)(ws + XGF),
            640, lengths, coffp);
        lstm1_k<<<dim3(64, 1), 640, 0, stream>>>(
            (const f16*)(ws + XGF), (const f16*)(ws + XGF),
            (const f16*)(ws + H1B), (const f16*)(ws + H1B),
            (float*)(ws + SENT), lengths, coffp, 1);
    }

    k4a<<<1024, 64, 0, stream>>>((const float*)(ws + SENT), w_ex, b_ex, lab,
                                 (float*)(ws + A2), (int*)(ws + EXP));
    gemm_mlp<<<8, 256, 0, stream>>>((const float*)(ws + A2), 640, 20,
                                    (const f16*)(ws + WMLP), b_mlp,
                                    (float*)(ws + JNT), 320);
    k5<<<1, 1024, 0, stream>>>((const float*)(ws + JNT), (const float*)(ws + SENT),
                               w_sc, b_sc, gold, (const int*)(ws + EXP),
                               (float*)(ws + MIX), (float*)(ws + PEN), dout);

    // LSTM2 input gates: bias folded via MIX col 300 == 1.0
    gemm2_nt<false><<<dim3(8, 4), 256, 0, stream>>>(
        (const float*)(ws + MIX), 320, 320, 10, -1,
        (const f16*)(ws + W2F), (f16*)(ws + G2F),
        (const f16*)(ws + W2B), (f16*)(ws + G2B),
        640, nullptr, nullptr);
    lstm2_k<<<2, 640, 0, stream>>>((const f16*)(ws + G2F), (const f16*)(ws + G2B),
                                   (const f16*)(ws + H2F), (const f16*)(ws + H2B),
                                   (float*)(ws + OUT2));

    k8<<<8, 256, 0, stream>>>((const float*)(ws + OUT2), w_tag, b_tag, gold,
                              (const float*)(ws + PEN), dout);
}